// Round 7
// baseline (114.279 us; speedup 1.0000x reference)
//
#include <hip/hip_runtime.h>
#include <hip/hip_bf16.h>

// out[b,d,r] = sum_c p[b,c] * softmax_d( x[b,:] @ W[:, c*8+d, r] + bias[c,d,r] )
// B=16384, F=128, C=8, R=64.  bf16 MFMA 32x32x16, fully fused.
//
// R16->R17: R14/R15/R16 all land at ~35-37us fused despite opposite schedule
// structures -> throughput-bound on per-wave work, not convoy-bound.  The
// 16x16x32 shape's floor: 16B of ds_read B-frag per output (512KB/CU/c,
// ~6.1kcyc LDS-pipe) + 32 exp2 + ~140 VALU softmax per wave per c.
// R17 switches to mfma_f32_32x32x16_bf16 with x as the B-operand
// (batch-in-columns):
//  - wave = 32 rows((d,rr) combos) x 32 cols(batch): 8B LDS/output (2x less),
//    8192 waves (2x more, ~20/CU at ~90 regs).
//  - C/D row m=(reg&3)+8*(reg>>2)+4*half -> pack (d=m&7, rr=m>>3): softmax
//    over d = 3 in-lane adds + ONE shfl_xor(32) per r2-group; p[b,c] is one
//    coalesced load/c from a transposed pT (prepass).
//  - stores register-direct: regs {q,q+4,q+8,q+12} = one 16B (b,d,r-chunk)
//    dwordx4; 4 stores/wave; L2 combines lines across same-XCD w-blocks.
//  - R14's proven one-barrier/c 2x8KB double-buffer; bias pre-permuted to
//    C/D row order (bias_r, 4 float4/c, folded into MFMA C-in); LOG2E
//    pre-folded into W and bias (softmax = exp2 direct, exact).

#define F_DIM    128
#define NCOL     4096      // C*C*R
#define OUT_STRIDE 512     // C*R
#define LOG2E    1.44269504088896340736f

typedef __bf16 bf16x8 __attribute__((ext_vector_type(8)));
typedef float  f32x4  __attribute__((ext_vector_type(4)));
typedef float  f32x16 __attribute__((ext_vector_type(16)));

#define AS1(p) ((const __attribute__((address_space(1))) unsigned int*)(p))
#define AS3(p) ((__attribute__((address_space(3))) unsigned int*)(p))

// ---------------------------------------------------------------------------
// Prepass: W fp32 (128 x 4096 row-major) -> bf16 A-operand fragments for
// mfma_f32_32x32x16_bf16, pre-scaled by log2(e).
// Fragment gf = (c*16 + w4)*8 + kst: lane l holds A[row m = l&31]
// [k = kst*16 + (l>>5)*8 + j], j=0..7, where row m maps to column
// n = c*512 + (m&7)*64 + w4*4 + (m>>3)   (d = m&7, rr = m>>3).
// Also emits pT[c][b] = p[b][c] (8 x 16384) and bias_r[(c*16+w4)*32 + m] =
// bias[c][m&7][w4*4 + m>>3] * log2e (C/D-row-ordered bias).
// ---------------------------------------------------------------------------
__global__ void wconv_kernel(const float* __restrict__ W,
                             const float* __restrict__ p,
                             const float* __restrict__ bias,
                             __bf16* __restrict__ wf,
                             float* __restrict__ pT,
                             float* __restrict__ bias_r) {
    int f    = blockIdx.x * 256 + threadIdx.x;  // 0..65535
    int lane = f & 63;
    int gf   = f >> 6;          // fragment id 0..1023
    int kst  = gf & 7;
    int w4   = (gf >> 3) & 15;
    int c    = gf >> 7;
    int m    = lane & 31;
    int kbase = kst * 16 + (lane >> 5) * 8;
    int n     = c * 512 + (m & 7) * 64 + w4 * 4 + (m >> 3);
    bf16x8 frag;
#pragma unroll
    for (int j = 0; j < 8; ++j)
        frag[j] = (__bf16)(W[(kbase + j) * NCOL + n] * LOG2E);
    *(bf16x8*)(wf + (size_t)f * 8) = frag;

    // pT: 131072 elements, 2 per thread (coalesced writes, gathered reads)
#pragma unroll
    for (int u = f; u < 131072; u += 65536)
        pT[u] = p[(size_t)(u & 16383) * 8 + (u >> 14)];

    // bias_r: 4096 elements
    if (f < 4096) {
        int cc = f >> 9, ww4 = (f >> 5) & 15, mm = f & 31;
        bias_r[f] = bias[cc * 512 + (mm & 7) * 64 + ww4 * 4 + (mm >> 3)] * LOG2E;
    }
}

// ---------------------------------------------------------------------------
// Fused GEMM + bias + softmax(d) + p-contraction.  mfma 32x32x16.
// Block: 256 thr (4 waves), 128 batch cols, one 4-r chunk w4 = blockIdx>>7.
// Wave ww owns batch cols b0w..b0w+32.  Per c: 8 A-fragments (8 KB) double-
// buffer-staged (wave ww stages kst=2ww,2ww+1); x lives in registers as the
// B-operand for the whole kernel (xfr[8], 32 VGPR).  acc = one f32x16;
// softmax over d: per r2-group 3 in-lane adds + 1 shfl_xor(32); C-in=bias_r.
// Stores: regs {q,q+4,q+8,q+12} = out[b][(q+4h)*64 + w4*4 .. +4] dwordx4.
// w-major grid: XCD = g%8, all 16 w4-chunks of a row-group on one XCD.
// ---------------------------------------------------------------------------
__global__ __launch_bounds__(256, 5)
void fused_kernel(const float* __restrict__ x, const float* __restrict__ pT,
                  const float* __restrict__ bias_r, const __bf16* __restrict__ wf,
                  float* __restrict__ out) {
    __shared__ __align__(16) char lds[16384];   // 2 x (8 fragments = 8 KB)

    const int lane = threadIdx.x & 63;
    const int ww   = threadIdx.x >> 6;   // wave 0..3
    const int l31  = lane & 31;          // batch col within wave
    const int h    = lane >> 5;          // half: contributes +4 to C/D row
    const int w4   = blockIdx.x >> 7;    // 4-r chunk 0..15 (w-major)
    const int g    = blockIdx.x & 127;   // batch group
    const int b0w  = g * 128 + ww * 32;

    // ---- prologue: stage c=0 into buffer 0 (wave ww stages kst=2ww,2ww+1) -
#pragma unroll
    for (int s = 0; s < 2; ++s) {
        int kst = ww * 2 + s;
        int gfr = w4 * 8 + kst;          // c = 0
        __builtin_amdgcn_global_load_lds(
            AS1((const char*)wf + (size_t)gfr * 1024 + lane * 16),
            AS3(lds + kst * 1024), 16, 0, 0);
    }

    // x B-fragments: xfr[kst][j] = x_bf16[b0w + l31][kst*16 + h*8 + j]
    bf16x8 xfr[8];
    {
        const float* xr = x + (size_t)(b0w + l31) * F_DIM + h * 8;
#pragma unroll
        for (int kst = 0; kst < 8; ++kst) {
            float4 lo = *(const float4*)(xr + kst * 16);
            float4 hi = *(const float4*)(xr + kst * 16 + 4);
            bf16x8 fr;
            fr[0] = (__bf16)lo.x; fr[1] = (__bf16)lo.y;
            fr[2] = (__bf16)lo.z; fr[3] = (__bf16)lo.w;
            fr[4] = (__bf16)hi.x; fr[5] = (__bf16)hi.y;
            fr[6] = (__bf16)hi.z; fr[7] = (__bf16)hi.w;
            xfr[kst] = fr;
        }
    }

    float O[16] = {};   // [reg] output accumulator over c (row m per reg)

#pragma unroll 1
    for (int c = 0; c < 8; ++c) {
        // barrier: stage(c) landed (issued a full phase ago) AND all waves
        // done reading buf[(c+1)&1] from iteration c-1.
        __syncthreads();

        // ---- issue stage(c+1) into the other buffer (hides under compute)
        if (c < 7) {
            char* dst = lds + ((c + 1) & 1) * 8192;
#pragma unroll
            for (int s = 0; s < 2; ++s) {
                int kst = ww * 2 + s;
                int gfr = ((c + 1) * 16 + w4) * 8 + kst;
                __builtin_amdgcn_global_load_lds(
                    AS1((const char*)wf + (size_t)gfr * 1024 + lane * 16),
                    AS3(dst + kst * 1024), 16, 0, 0);
            }
        }

        // ---- p (one coalesced load) and bias (4x float4), pre-MFMA --------
        float pv = pT[(size_t)c * 16384 + b0w + l31];

        f32x4 bvl[4];
#pragma unroll
        for (int r2 = 0; r2 < 4; ++r2)
            bvl[r2] = *(const f32x4*)(bias_r + (c * 16 + w4) * 32 + r2 * 8 + h * 4);

        // C-in = bias_r (row m = (i&3) + 8*(i>>2) + 4h; col-invariant)
        f32x16 acc;
#pragma unroll
        for (int i = 0; i < 16; ++i)
            acc[i] = bvl[i >> 2][i & 3];

        const char* buf = lds + (c & 1) * 8192;
#pragma unroll
        for (int kst = 0; kst < 8; ++kst) {
            bf16x8 af = *(const bf16x8*)(buf + kst * 1024 + lane * 16);
            acc = __builtin_amdgcn_mfma_f32_32x32x16_bf16(af, xfr[kst], acc, 0, 0, 0);
        }

        // ---- softmax over d (= (i&3) + 4h) + p-weighted accumulate --------
#pragma unroll
        for (int r2 = 0; r2 < 4; ++r2) {
            float e0 = __builtin_amdgcn_exp2f(acc[r2 * 4 + 0]);
            float e1 = __builtin_amdgcn_exp2f(acc[r2 * 4 + 1]);
            float e2 = __builtin_amdgcn_exp2f(acc[r2 * 4 + 2]);
            float e3 = __builtin_amdgcn_exp2f(acc[r2 * 4 + 3]);
            float s4 = (e0 + e1) + (e2 + e3);       // this half's 4 d's
            float s8 = s4 + __shfl_xor(s4, 32, 64); // + other half's 4 d's
            float scale = pv * __builtin_amdgcn_rcpf(s8);
            O[r2 * 4 + 0] = __builtin_fmaf(e0, scale, O[r2 * 4 + 0]);
            O[r2 * 4 + 1] = __builtin_fmaf(e1, scale, O[r2 * 4 + 1]);
            O[r2 * 4 + 2] = __builtin_fmaf(e2, scale, O[r2 * 4 + 2]);
            O[r2 * 4 + 3] = __builtin_fmaf(e3, scale, O[r2 * 4 + 3]);
        }
        // no second barrier: next iteration's __syncthreads covers the
        // write-after-read hazard on buf[(c+1)&1].
    }

    // ---- stores: regs {q, q+4, q+8, q+12} = rr 0..3 for d = q+4h ----------
    // out[b0w+l31][(q+4h)*64 + w4*4 + rr]: one 16B dwordx4 per q.
#pragma unroll
    for (int q = 0; q < 4; ++q) {
        f32x4 v = {O[q], O[4 + q], O[8 + q], O[12 + q]};
        *(f32x4*)(out + (size_t)(b0w + l31) * OUT_STRIDE + (q + 4 * h) * 64 + w4 * 4) = v;
    }
}

extern "C" void kernel_launch(void* const* d_in, const int* in_sizes, int n_in,
                              void* d_out, int out_size, void* d_ws, size_t ws_size,
                              hipStream_t stream) {
    const float* x    = (const float*)d_in[0];   // (16384, 128)
    const float* p    = (const float*)d_in[1];   // (16384, 8)
    const float* W    = (const float*)d_in[2];   // (128, 64, 64)
    const float* bias = (const float*)d_in[3];   // (8, 8, 64)
    float* out = (float*)d_out;                  // (16384, 8, 64)
    __bf16* wf     = (__bf16*)d_ws;                          // 1 MB fragments
    float*  pT     = (float*)((char*)d_ws + (1 << 20));      // 512 KB p^T
    float*  bias_r = (float*)((char*)d_ws + (1 << 20) + (512 << 10)); // 16 KB

    wconv_kernel<<<dim3(256), dim3(256), 0, stream>>>(W, p, bias, wf, pT, bias_r);
    fused_kernel<<<dim3(2048), dim3(256), 0, stream>>>(x, pT, bias_r, wf, out);
}

// Round 8
// 97.898 us; speedup vs baseline: 1.1673x; 1.1673x over previous
//
#include <hip/hip_runtime.h>
#include <hip/hip_bf16.h>

// out[b,d,r] = sum_c p[b,c] * softmax_d( x[b,:] @ W[:, c*8+d, r] + bias[c,d,r] )
// B=16384, F=128, C=8, R=64.  bf16 MFMA 16x16x32, fully fused.
//
// R17->R18: R17 (32x32x16, batch-in-cols) regressed to 53.6us: one serial
// 8-MFMA dependent chain (no ILP) + 16B-fragment stores (WRITE_SIZE 91MB =
// 2.7x amp).  Reverted.  R14 (34us fused) is the champion; R12/R15/R17 show
// it is NOT LDS-BW bound (less-traffic variants didn't win) -- it runs at
// ~1.7x its 20.5us LDS floor because each wave's ~580cyc softmax dep chain
// (36 transcendentals) serializes AFTER its ds_read stream, idling the LDS
// pipe.  R18 keeps the R14 shell verbatim and only improves per-c overlap:
//  - d-outer MFMA loop: acc[d] completes after its 4 chained MFMAs, so
//    exp2(acc[d]) (computed IN PLACE, no e[] array) can interleave under
//    d+1..7's ds_reads.  8 independent d-chains keep the old MFMA ILP.
//  - LOG2E folded into prepass (W*log2e, biasT*log2e; exact, R16-proven):
//    softmax = exp2(acc) direct, kills 32 v_mul/wave/c.
//  - bias transposed in prepass to biasT[c][r][8d]: 8 scalar loads -> 2
//    f32x4 loads per c.
// Everything else proven-and-kept: 512thr/8wave blocks, grid 512 (2 blk/CU,
// 16 waves/CU), 2x32KB LDS ring, ONE barrier/c with stage(c+1) issued right
// after it, w-major grid (XCD locality), bias as MFMA C-in, in-lane softmax
// (zero shuffles), full 64B-line stores.

#define F_DIM    128
#define NCOL     4096      // C*C*R
#define OUT_STRIDE 512     // C*R
#define LOG2E    1.44269504088896340736f

typedef __bf16 bf16x8 __attribute__((ext_vector_type(8)));
typedef float  f32x4  __attribute__((ext_vector_type(4)));

#define AS1(p) ((const __attribute__((address_space(1))) unsigned int*)(p))
#define AS3(p) ((__attribute__((address_space(3))) unsigned int*)(p))

// ---------------------------------------------------------------------------
// Prepass: W fp32 (128 x 4096 row-major) -> bf16 MFMA B-fragments, PRE-SCALED
// by log2(e).  Tile t in [0,256) covers cols t*16..t*16+16; fragment (t,kk)
// holds k = kk*32 + (lane>>4)*8 + j, n = t*16 + (lane&15), at wf[(t*4+kk)*512].
// Also emits biasT[(c*64 + r)*8 + d] = bias[c][d][r] * log2e  (16 KB).
// ---------------------------------------------------------------------------
__global__ void wconv_kernel(const float* __restrict__ W,
                             const float* __restrict__ bias,
                             __bf16* __restrict__ wf,
                             float* __restrict__ biasT) {
    int f    = blockIdx.x * 256 + threadIdx.x;  // 0..65535
    int lane = f & 63;
    int tkk  = f >> 6;
    int t    = tkk >> 2;
    int kk   = tkk & 3;
    int kbase = kk * 32 + (lane >> 4) * 8;
    int n     = t * 16 + (lane & 15);
    bf16x8 frag;
#pragma unroll
    for (int j = 0; j < 8; ++j)
        frag[j] = (__bf16)(W[(kbase + j) * NCOL + n] * LOG2E);
    *(bf16x8*)(wf + (size_t)f * 8) = frag;

    if (f < 4096) {   // biasT: [c][r][d]
        int c = f >> 9, r = (f >> 3) & 63, d = f & 7;
        biasT[f] = bias[(c * 8 + d) * 64 + r] * LOG2E;
    }
}

// ---------------------------------------------------------------------------
// Fused GEMM + bias + softmax(d) + p-contraction.
// Block: 512 thr (8 waves), 128 batch rows, one 16-r chunk w = blockIdx>>7.
// Wave ww owns rows b0..b0+16.  Per c: 32 fragments (8 d x 4 kk, 32 KB)
// double-buffer-staged (wave ww stages d=ww's 4 kk frags); each wave reads
// all 32 (block-shared).  d-OUTER mfma loop -> acc[d] done early -> in-place
// exp2 overlaps later d's ds_reads.  Softmax in-lane (7-add tree, 1 rcp,
// 8 fma per jj, zero shuffles, zero muls).  C-in = biasT (2 f32x4 loads).
// C/D layout: col=lane&15 -> r, row=quad*4+jj -> batch row.
// ---------------------------------------------------------------------------
__global__ __launch_bounds__(512, 4)
void fused_kernel(const float* __restrict__ x, const float* __restrict__ p,
                  const float* __restrict__ biasT, const __bf16* __restrict__ wf,
                  float* __restrict__ out) {
    __shared__ __align__(16) char lds[65536];   // 2 x (32 fragments = 32 KB)

    const int lane = threadIdx.x & 63;
    const int ww   = threadIdx.x >> 6;   // wave 0..7 = m-tile, also staged d
    const int quad = lane >> 4;
    const int l15  = lane & 15;
    const int w    = blockIdx.x >> 7;    // r-chunk 0..3 (w-major: XCD = g%8)
    const int g    = blockIdx.x & 127;   // row-group
    const int b0   = g * 128 + ww * 16;

    // ---- prologue: stage c=0 into buffer 0 (wave ww stages d=ww) ----------
    {
        const __bf16* src = wf + (size_t)((ww * 4 + w) * 4) * 512 + lane * 8;
#pragma unroll
        for (int kk = 0; kk < 4; ++kk)
            __builtin_amdgcn_global_load_lds(
                AS1(src + kk * 512),
                AS3(lds + (ww * 4 + kk) * 1024), 16, 0, 0);
    }

    // A fragments: afr[kk][j] = x_bf16[b0+l15][kk*32 + quad*8 + j]
    bf16x8 afr[4];
    {
        const float* xr = x + (size_t)(b0 + l15) * F_DIM + quad * 8;
#pragma unroll
        for (int kk = 0; kk < 4; ++kk) {
            float4 lo = *(const float4*)(xr + kk * 32);
            float4 hi = *(const float4*)(xr + kk * 32 + 4);
            bf16x8 f;
            f[0] = (__bf16)lo.x; f[1] = (__bf16)lo.y;
            f[2] = (__bf16)lo.z; f[3] = (__bf16)lo.w;
            f[4] = (__bf16)hi.x; f[5] = (__bf16)hi.y;
            f[6] = (__bf16)hi.z; f[7] = (__bf16)hi.w;
            afr[kk] = f;
        }
    }

    float O[8][4] = {};   // [d][jj] output accumulator over c

#pragma unroll 1
    for (int c = 0; c < 8; ++c) {
        // barrier: stage(c) landed (its loads had the whole previous compute
        // phase in flight) AND all waves done reading buf[(c+1)&1].
        __syncthreads();

        // ---- issue stage(c+1) into the other buffer (hides under compute)
        if (c < 7) {
            const __bf16* src =
                wf + (size_t)((((c + 1) * 8 + ww) * 4 + w) * 4) * 512 + lane * 8;
            char* dst = lds + ((c + 1) & 1) * 32768;
#pragma unroll
            for (int kk = 0; kk < 4; ++kk)
                __builtin_amdgcn_global_load_lds(
                    AS1(src + kk * 512),
                    AS3(dst + (ww * 4 + kk) * 1024), 16, 0, 0);
        }

        // ---- p and bias loads issued before MFMAs (latency hides under them)
        float pvv[4];
#pragma unroll
        for (int jj = 0; jj < 4; ++jj)
            pvv[jj] = p[(size_t)(b0 + quad * 4 + jj) * 8 + c];

        f32x4 bv0 = *(const f32x4*)(biasT + (c * 64 + w * 16 + l15) * 8);
        f32x4 bv1 = *(const f32x4*)(biasT + (c * 64 + w * 16 + l15) * 8 + 4);

        // ---- d-outer MFMA: 8 independent 4-chains; acc[d] finishes early --
        const char* buf = lds + (c & 1) * 32768;
        f32x4 acc[8];
#pragma unroll
        for (int d = 0; d < 8; ++d) {
            float bvd = (d < 4) ? bv0[d & 3] : bv1[d & 3];
            f32x4 a = {bvd, bvd, bvd, bvd};   // C-in = bias (row-invariant)
#pragma unroll
            for (int kk = 0; kk < 4; ++kk) {
                bf16x8 bfr = *(const bf16x8*)(buf + (d * 4 + kk) * 1024 + lane * 16);
                a = __builtin_amdgcn_mfma_f32_16x16x32_bf16(afr[kk], bfr, a, 0, 0, 0);
            }
            acc[d] = a;
        }

        // ---- in-place exp2 (interleaves upward under later d's ds_reads) --
#pragma unroll
        for (int d = 0; d < 8; ++d)
#pragma unroll
            for (int jj = 0; jj < 4; ++jj)
                acc[d][jj] = __builtin_amdgcn_exp2f(acc[d][jj]);

        // ---- softmax denominator + p-weighted accumulate ------------------
#pragma unroll
        for (int jj = 0; jj < 4; ++jj) {
            float s01 = acc[0][jj] + acc[1][jj], s23 = acc[2][jj] + acc[3][jj];
            float s45 = acc[4][jj] + acc[5][jj], s67 = acc[6][jj] + acc[7][jj];
            float s = (s01 + s23) + (s45 + s67);
            float scale = pvv[jj] * __builtin_amdgcn_rcpf(s);
#pragma unroll
            for (int d = 0; d < 8; ++d)
                O[d][jj] = __builtin_fmaf(acc[d][jj], scale, O[d][jj]);
        }
        // no second barrier: next iteration's __syncthreads covers the
        // write-after-read hazard on buf[(c+1)&1].
    }

    // ---- stores: out[b, d*64 + w*16 + l15] — 64B per quad, full lines -----
#pragma unroll
    for (int jj = 0; jj < 4; ++jj) {
        float* orow = out + (size_t)(b0 + quad * 4 + jj) * OUT_STRIDE + w * 16 + l15;
#pragma unroll
        for (int d = 0; d < 8; ++d)
            orow[d * 64] = O[d][jj];
    }
}

extern "C" void kernel_launch(void* const* d_in, const int* in_sizes, int n_in,
                              void* d_out, int out_size, void* d_ws, size_t ws_size,
                              hipStream_t stream) {
    const float* x    = (const float*)d_in[0];   // (16384, 128)
    const float* p    = (const float*)d_in[1];   // (16384, 8)
    const float* W    = (const float*)d_in[2];   // (128, 64, 64)
    const float* bias = (const float*)d_in[3];   // (8, 8, 64)
    float* out = (float*)d_out;                  // (16384, 8, 64)
    __bf16* wf    = (__bf16*)d_ws;               // 1 MB bf16 fragments
    float*  biasT = (float*)((char*)d_ws + (1 << 20));  // 16 KB scaled bias

    wconv_kernel<<<dim3(256), dim3(256), 0, stream>>>(W, bias, wf, biasT);
    fused_kernel<<<dim3(512), dim3(512), 0, stream>>>(x, p, biasT, wf, out);
}